// Round 3
// baseline (789.228 us; speedup 1.0000x reference)
//
#include <hip/hip_runtime.h>
#include <math.h>

#define HID 128
#define HEADS 8
#define MAXE 128

// ---------------- split-K GEMM: C(atomic) += A[:,kz]@B[kz,:] ; 64x64 tile, 4x4/thread --------
__global__ __launch_bounds__(256) void gemm_splitk(
    const float* __restrict__ A, const float* __restrict__ B,
    float* __restrict__ C, int M, int N, int K, int kchunk)
{
  __shared__ float As[16][68];  // [k][m], padded
  __shared__ float Bs[16][68];  // [k][n], padded
  const int tid = threadIdx.x;
  const int bm = blockIdx.y * 64;
  const int bn = blockIdx.x * 64;
  const int kbeg = blockIdx.z * kchunk;
  const int kend = kbeg + kchunk;
  const int tx = tid & 15, ty = tid >> 4;
  const int a_row = tid >> 2, a_col = (tid & 3) << 2;
  const int b_row = tid >> 4, b_col = (tid & 15) << 2;
  float acc[4][4];
#pragma unroll
  for (int i = 0; i < 4; i++)
#pragma unroll
    for (int j = 0; j < 4; j++) acc[i][j] = 0.f;

  const int gr = bm + a_row;
  for (int k0 = kbeg; k0 < kend; k0 += 16) {
    float4 av = make_float4(0.f, 0.f, 0.f, 0.f);
    if (gr < M) av = *(const float4*)(A + (size_t)gr * K + (k0 + a_col));
    As[a_col + 0][a_row] = av.x;
    As[a_col + 1][a_row] = av.y;
    As[a_col + 2][a_row] = av.z;
    As[a_col + 3][a_row] = av.w;
    float4 bv = *(const float4*)(B + (size_t)(k0 + b_row) * N + (bn + b_col));
    *(float4*)&Bs[b_row][b_col] = bv;
    __syncthreads();
#pragma unroll
    for (int kk = 0; kk < 16; kk++) {
      float4 a4 = *(const float4*)&As[kk][ty << 2];
      float4 b4 = *(const float4*)&Bs[kk][tx << 2];
      float ar[4] = {a4.x, a4.y, a4.z, a4.w};
      float br[4] = {b4.x, b4.y, b4.z, b4.w};
#pragma unroll
      for (int i = 0; i < 4; i++)
#pragma unroll
        for (int j = 0; j < 4; j++) acc[i][j] = fmaf(ar[i], br[j], acc[i][j]);
    }
    __syncthreads();
  }
#pragma unroll
  for (int i = 0; i < 4; i++) {
    int r = bm + (ty << 2) + i;
    if (r < M) {
      float* cp = C + (size_t)r * N + bn + (tx << 2);
#pragma unroll
      for (int j = 0; j < 4; j++) atomicAdd(cp + j, acc[i][j]);
    }
  }
}

// ---------------- epilogue: C = act(C*scale + bias[col]), in place, N==128 ----------------
__global__ __launch_bounds__(256) void scale_bias_act(
    float* __restrict__ C, const float* __restrict__ bias,
    int total4, float scale, int do_relu)
{
  int gid = blockIdx.x * 256 + threadIdx.x;
  if (gid >= total4) return;
  float4 v = *(float4*)(C + (size_t)gid * 4);
  const float4 b = *(const float4*)(bias + ((gid * 4) & (HID - 1)));
  v.x = v.x * scale + b.x;
  v.y = v.y * scale + b.y;
  v.z = v.z * scale + b.z;
  v.w = v.w * scale + b.w;
  if (do_relu) {
    v.x = v.x > 0.f ? v.x : 0.f;
    v.y = v.y > 0.f ? v.y : 0.f;
    v.z = v.z > 0.f ? v.z : 0.f;
    v.w = v.w > 0.f ? v.w : 0.f;
  }
  *(float4*)(C + (size_t)gid * 4) = v;
}

// ---------------- upfront weight prep: 4x permute_w + 8x make_v in one launch ----------------
struct PrepArgs {
  const float* W[8];   // Ws0,Wd0,Ws1,Wd1,Ws2,Wd2,Ws3,Wd3
  const float* a[8];
  float* Wp[4];
  float* v[8];
};

__global__ __launch_bounds__(256) void prep_weights(PrepArgs p)
{
  int bid = blockIdx.x;
  if (bid < 2048) {  // permute: Wp[g][(h*128+k)*128+c] = Ws[g][k*1024+h*128+c]
    int g = bid >> 9;
    int idx = ((bid & 511) << 8) + threadIdx.x;   // 0..131071
    int c = idx & (HID - 1);
    int kk = idx >> 7;
    int h = kk >> 7, k = kk & (HID - 1);
    p.Wp[g][idx] = p.W[2 * g][(size_t)k * (HEADS * HID) + h * HID + c];
  } else {           // make_v: v[wi][k*8+h] = sum_c W[wi][k, h*128+c] * a[wi][h,c]
    int u = bid - 2048;
    int wi = u >> 2;
    int gid = ((u & 3) << 8) + threadIdx.x;       // 0..1023
    int k = gid >> 3, h = gid & 7;
    const float* wr = p.W[wi] + (size_t)k * (HEADS * HID) + h * HID;
    const float* ar = p.a[wi] + (size_t)h * HID;
    float s = 0.f;
    for (int c = 0; c < HID; c++) s = fmaf(wr[c], ar[c], s);
    p.v[wi][gid] = s;
  }
}

// ---------------- al_s and al_d in one launch ----------------
__global__ __launch_bounds__(256) void compute_al2(
    const float* __restrict__ hsrc, const float* __restrict__ hdst,
    const float* __restrict__ vs_, const float* __restrict__ vd_,
    float* __restrict__ als, float* __restrict__ ald, int nsrc, int ndst)
{
  __shared__ float vsh[2 * HID * HEADS];
  for (int i = threadIdx.x; i < 2 * HID * HEADS; i += 256)
    vsh[i] = (i < HID * HEADS) ? vs_[i] : vd_[i - HID * HEADS];
  __syncthreads();
  int gid = blockIdx.x * 256 + threadIdx.x;
  int row = gid >> 3, h = gid & 7;
  if (row < nsrc) {
    const float* hr = hsrc + (size_t)row * HID;
    float s = 0.f;
    for (int k = 0; k < HID; k++) s = fmaf(hr[k], vsh[k * HEADS + h], s);
    als[gid] = s;
  } else if (row < nsrc + ndst) {
    int r = row - nsrc;
    const float* hr = hdst + (size_t)r * HID;
    float s = 0.f;
    for (int k = 0; k < HID; k++) s = fmaf(hr[k], vsh[HID * HEADS + k * HEADS + h], s);
    ald[(size_t)r * HEADS + h] = s;
  }
}

// ---------------- CSR build (both directions fused) ----------------
__global__ __launch_bounds__(256) void hist2(
    const int* __restrict__ dst_ab, const int* __restrict__ dst_ba,
    int* __restrict__ cnt_ab, int* __restrict__ cnt_ba, int E)
{
  int gid = blockIdx.x * 256 + threadIdx.x;
  if (gid < E) atomicAdd(&cnt_ab[dst_ab[gid]], 1);
  else if (gid < 2 * E) atomicAdd(&cnt_ba[dst_ba[gid - E]], 1);
}

__global__ __launch_bounds__(1024) void scan2(
    const int* __restrict__ cnt_ab, const int* __restrict__ cnt_ba,
    int* __restrict__ ip_ab, int* __restrict__ ip_ba, int n_ab, int n_ba)
{
  const int* cnt = (blockIdx.x == 0) ? cnt_ab : cnt_ba;
  int* indptr = (blockIdx.x == 0) ? ip_ab : ip_ba;
  int n = (blockIdx.x == 0) ? n_ab : n_ba;
  __shared__ int parts[1024];
  const int tid = threadIdx.x;
  const int base = tid * 10;
  int local[10];
  int s = 0;
#pragma unroll
  for (int j = 0; j < 10; j++) {
    int v = (base + j < n) ? cnt[base + j] : 0;
    local[j] = v; s += v;
  }
  parts[tid] = s;
  __syncthreads();
  for (int off = 1; off < 1024; off <<= 1) {
    int v = (tid >= off) ? parts[tid - off] : 0;
    __syncthreads();
    parts[tid] += v;
    __syncthreads();
  }
  int ex = parts[tid] - s;
#pragma unroll
  for (int j = 0; j < 10; j++) {
    if (base + j < n) indptr[base + j] = ex;
    ex += local[j];
  }
  if (tid == 1023) indptr[n] = parts[1023];
}

__global__ __launch_bounds__(256) void scatter2(
    const int* __restrict__ edge_ab, const int* __restrict__ edge_ba,
    const int* __restrict__ ip_ab, const int* __restrict__ ip_ba,
    int* __restrict__ cur_ab, int* __restrict__ cur_ba,
    int* __restrict__ srcs_ab, int* __restrict__ srcs_ba, int E)
{
  int gid = blockIdx.x * 256 + threadIdx.x;
  if (gid < E) {
    int d = edge_ab[E + gid];
    int pos = ip_ab[d] + atomicAdd(&cur_ab[d], 1);
    srcs_ab[pos] = edge_ab[gid];
  } else if (gid < 2 * E) {
    int g = gid - E;
    int d = edge_ba[E + g];
    int pos = ip_ba[d] + atomicAdd(&cur_ba[d], 1);
    srcs_ba[pos] = edge_ba[g];
  }
}

// ---------------- per-dst segment softmax + aggregation; logits cached in LDS ----------------
__global__ __launch_bounds__(128) void gat_edge(
    const int* __restrict__ indptr, const int* __restrict__ srcs,
    const float* __restrict__ al_s, const float* __restrict__ al_d,
    const float* __restrict__ h_src, float* __restrict__ z, int ndst)
{
  const int n = blockIdx.x;
  const int tid = threadIdx.x;
  __shared__ unsigned mu[HEADS];
  __shared__ float mf[HEADS], den[HEADS], aldn[HEADS];
  __shared__ float lw[MAXE][HEADS];
  __shared__ int es[MAXE];
  const int base = indptr[n];
  const int deg = indptr[n + 1] - base;
  if (tid < HEADS) {
    mu[tid] = 0u;
    den[tid] = 0.f;
    aldn[tid] = al_d[(size_t)n * HEADS + tid];
  }
  const bool fast = (deg <= MAXE);
  if (fast)
    for (int i = tid; i < deg; i += 128) es[i] = srcs[base + i];
  __syncthreads();

  float acc[HEADS];
#pragma unroll
  for (int h = 0; h < HEADS; h++) acc[h] = 0.f;

  if (fast) {
    const int tot = deg * HEADS;
    // pass 1: logits -> LDS, running max
    for (int i = tid; i < tot; i += 128) {
      int e = i >> 3, h = i & 7;
      float v = al_s[(size_t)es[e] * HEADS + h] + aldn[h];
      v = v > 0.f ? v : 0.2f * v;
      lw[e][h] = v;
      unsigned u = __float_as_uint(v);
      u = (u & 0x80000000u) ? ~u : (u | 0x80000000u);
      atomicMax(&mu[h], u);
    }
    __syncthreads();
    if (tid < HEADS) {
      unsigned u = mu[tid];
      mf[tid] = __uint_as_float((u & 0x80000000u) ? (u ^ 0x80000000u) : ~u);
    }
    __syncthreads();
    // pass 2: exp in place + denom
    for (int i = tid; i < tot; i += 128) {
      int e = i >> 3, h = i & 7;
      float ex = expf(lw[e][h] - mf[h]);
      lw[e][h] = ex;
      atomicAdd(&den[h], ex);
    }
    __syncthreads();
    // pass 3: normalize
    for (int i = tid; i < tot; i += 128) {
      int e = i >> 3, h = i & 7;
      lw[e][h] = lw[e][h] / (den[h] + 1e-16f);
    }
    __syncthreads();
    // aggregate: thread = channel c
    for (int e = 0; e < deg; e++) {
      float hv = h_src[(size_t)es[e] * HID + tid];
#pragma unroll
      for (int h = 0; h < HEADS; h++) acc[h] = fmaf(lw[e][h], hv, acc[h]);
    }
  } else {
    const int tot = deg * HEADS;
    for (int i = tid; i < tot; i += 128) {
      int e = i >> 3, h = i & 7;
      float v = al_s[(size_t)srcs[base + e] * HEADS + h] + aldn[h];
      v = v > 0.f ? v : 0.2f * v;
      unsigned u = __float_as_uint(v);
      u = (u & 0x80000000u) ? ~u : (u | 0x80000000u);
      atomicMax(&mu[h], u);
    }
    __syncthreads();
    if (tid < HEADS) {
      unsigned u = mu[tid];
      mf[tid] = __uint_as_float((u & 0x80000000u) ? (u ^ 0x80000000u) : ~u);
    }
    __syncthreads();
    for (int i = tid; i < tot; i += 128) {
      int e = i >> 3, h = i & 7;
      float v = al_s[(size_t)srcs[base + e] * HEADS + h] + aldn[h];
      v = v > 0.f ? v : 0.2f * v;
      atomicAdd(&den[h], expf(v - mf[h]));
    }
    __syncthreads();
    for (int e0 = 0; e0 < deg; e0 += MAXE) {
      int ne = deg - e0; if (ne > MAXE) ne = MAXE;
      for (int i = tid; i < ne; i += 128) es[i] = srcs[base + e0 + i];
      __syncthreads();
      for (int i = tid; i < ne * HEADS; i += 128) {
        int e = i >> 3, h = i & 7;
        float v = al_s[(size_t)es[e] * HEADS + h] + aldn[h];
        v = v > 0.f ? v : 0.2f * v;
        lw[e][h] = expf(v - mf[h]) / (den[h] + 1e-16f);
      }
      __syncthreads();
      for (int e = 0; e < ne; e++) {
        float hv = h_src[(size_t)es[e] * HID + tid];
#pragma unroll
        for (int h = 0; h < HEADS; h++) acc[h] = fmaf(lw[e][h], hv, acc[h]);
      }
      __syncthreads();
    }
  }
  float* zp = z + (size_t)n * (HEADS * HID) + tid;
#pragma unroll
  for (int h = 0; h < HEADS; h++) zp[h * HID] = acc[h];
}

// ---------------- pool: per-row dot, per-graph sums (both node sets in one launch) -------------
__global__ __launch_bounds__(256) void pool_dot2(
    const float* __restrict__ ha, const float* __restrict__ hb,
    const int* __restrict__ batch_a, const int* __restrict__ batch_b,
    const float* __restrict__ fc_w, float* __restrict__ gsum, int na, int nb)
{
  const bool isA = blockIdx.x < 160;
  const float* h = isA ? ha : hb;
  const int* batch = isA ? batch_a : batch_b;
  const float* wseg = isA ? fc_w : fc_w + HID;
  float* gs = isA ? gsum : gsum + 8;
  const int n = isA ? na : nb;
  const int b = isA ? blockIdx.x : blockIdx.x - 160;

  __shared__ float sg[8];
  if (threadIdx.x < 8) sg[threadIdx.x] = 0.f;
  __syncthreads();
  const int lane = threadIdx.x & 63;
  const int wv = threadIdx.x >> 6;
  const int gw = b * 4 + wv;
  const int tw = 160 * 4;
  const float2 w2 = *(const float2*)(wseg + lane * 2);
  for (int r = gw; r < n; r += tw) {
    float2 hv = *(const float2*)(h + (size_t)r * HID + lane * 2);
    float s = hv.x * w2.x + hv.y * w2.y;
#pragma unroll
    for (int off = 32; off > 0; off >>= 1) s += __shfl_down(s, off, 64);
    if (lane == 0) atomicAdd(&sg[batch[r]], s);
  }
  __syncthreads();
  if (threadIdx.x < 8) atomicAdd(&gs[threadIdx.x], sg[threadIdx.x]);
}

__global__ __launch_bounds__(64) void finalize_out(
    const float* __restrict__ gsum, const int* __restrict__ batch_a,
    const int* __restrict__ batch_b, const float* __restrict__ fc_b,
    float* __restrict__ out, int na, int nb, int ng)
{
  int g = threadIdx.x;
  if (g >= ng) return;
  int l, r, lo;
  l = 0; r = na; while (l < r) { int m = (l + r) >> 1; if (batch_a[m] < g) l = m + 1; else r = m; } lo = l;
  r = na; while (l < r) { int m = (l + r) >> 1; if (batch_a[m] < g + 1) l = m + 1; else r = m; }
  int ca = l - lo; if (ca < 1) ca = 1;
  l = 0; r = nb; while (l < r) { int m = (l + r) >> 1; if (batch_b[m] < g) l = m + 1; else r = m; } lo = l;
  r = nb; while (l < r) { int m = (l + r) >> 1; if (batch_b[m] < g + 1) l = m + 1; else r = m; }
  int cb = l - lo; if (cb < 1) cb = 1;
  out[g] = gsum[g] / (float)ca + gsum[8 + g] / (float)cb + fc_b[0];
}

extern "C" void kernel_launch(void* const* d_in, const int* in_sizes, int n_in,
                              void* d_out, int out_size, void* d_ws, size_t ws_size,
                              hipStream_t stream)
{
  const float* x_a = (const float*)d_in[0];
  const float* x_b = (const float*)d_in[1];
  const int* edge_ab = (const int*)d_in[2];
  const int* edge_ba = (const int*)d_in[3];
  const int* batch_a = (const int*)d_in[4];
  const int* batch_b = (const int*)d_in[5];
  const float* lin_a_w = (const float*)d_in[6];
  const float* lin_a_b = (const float*)d_in[7];
  const float* lin_b_w = (const float*)d_in[8];
  const float* lin_b_b = (const float*)d_in[9];
  const float* fc_w = (const float*)d_in[10];
  const float* fc_b = (const float*)d_in[11];

  const int NA = in_sizes[4];
  const int NB = in_sizes[5];
  const int E  = in_sizes[2] / 2;
  const int FA = in_sizes[0] / NA;
  const int FB = in_sizes[1] / NB;
  const int NG = out_size;
  const int NMAX = NA > NB ? NA : NB;
  const int KS = 4;  // K-split factor

  char* w = (char*)d_ws;
  auto carve = [&](size_t bytes) -> void* {
    void* p = (void*)w;
    w += (bytes + 255) & ~(size_t)255;
    return p;
  };
  // contiguous zero-region: all GEMM outputs (split-K atomic targets) + gsum
  char* zero_beg = w;
  float* ha0 = (float*)carve((size_t)NA * HID * 4);
  float* hb0 = (float*)carve((size_t)NB * HID * 4);
  float* ha1 = (float*)carve((size_t)NA * HID * 4);
  float* hb1 = (float*)carve((size_t)NB * HID * 4);
  float* ha2 = (float*)carve((size_t)NA * HID * 4);
  float* hb2 = (float*)carve((size_t)NB * HID * 4);
  float* gsum = (float*)carve((size_t)16 * 4);
  size_t zero_bytes = (size_t)(w - zero_beg);

  float* z    = (float*)carve((size_t)NMAX * HEADS * HID * 4);
  float* al_s = (float*)carve((size_t)NMAX * HEADS * 4);
  float* al_d = (float*)carve((size_t)NMAX * HEADS * 4);
  float* Wp4  = (float*)carve((size_t)4 * HEADS * HID * HID * 4);
  float* vv   = (float*)carve((size_t)8 * HID * HEADS * 4);
  int* csrcnt = (int*)carve((size_t)4 * NMAX * 4);  // cnt_ab, cnt_ba, cur_ab, cur_ba
  int* indptr_ab = (int*)carve((size_t)(NB + 1) * 4);
  int* srcs_ab   = (int*)carve((size_t)E * 4);
  int* indptr_ba = (int*)carve((size_t)(NA + 1) * 4);
  int* srcs_ba   = (int*)carve((size_t)E * 4);
  if ((size_t)(w - (char*)d_ws) > ws_size) return;  // loud failure (out stays zero)

  int* cnt_ab = csrcnt;
  int* cnt_ba = csrcnt + NMAX;
  int* cur_ab = csrcnt + 2 * NMAX;
  int* cur_ba = csrcnt + 3 * NMAX;

  hipMemsetAsync(zero_beg, 0, zero_bytes, stream);
  hipMemsetAsync(csrcnt, 0, (size_t)4 * NMAX * 4, stream);

  // upfront weight prep (independent of everything else)
  PrepArgs pa;
  const int wi_idx[8] = {12, 13, 17, 18, 22, 23, 27, 28};
  const int ai_idx[8] = {14, 15, 19, 20, 24, 25, 29, 30};
  for (int i = 0; i < 8; i++) {
    pa.W[i] = (const float*)d_in[wi_idx[i]];
    pa.a[i] = (const float*)d_in[ai_idx[i]];
    pa.v[i] = vv + (size_t)i * HID * HEADS;
  }
  for (int g = 0; g < 4; g++) pa.Wp[g] = Wp4 + (size_t)g * HEADS * HID * HID;
  prep_weights<<<2048 + 32, 256, 0, stream>>>(pa);

  // CSR both directions
  hist2<<<(2 * E + 255) / 256, 256, 0, stream>>>(edge_ab + E, edge_ba + E, cnt_ab, cnt_ba, E);
  scan2<<<2, 1024, 0, stream>>>(cnt_ab, cnt_ba, indptr_ab, indptr_ba, NB, NA);
  scatter2<<<(2 * E + 255) / 256, 256, 0, stream>>>(
      edge_ab, edge_ba, indptr_ab, indptr_ba, cur_ab, cur_ba, srcs_ab, srcs_ba, E);

  // input linears: h = relu(x @ W + b), split-K + epilogue
  gemm_splitk<<<dim3(HID / 64, (NA + 63) / 64, KS), 256, 0, stream>>>(
      x_a, lin_a_w, ha0, NA, HID, FA, FA / KS);
  gemm_splitk<<<dim3(HID / 64, (NB + 63) / 64, KS), 256, 0, stream>>>(
      x_b, lin_b_w, hb0, NB, HID, FB, FB / KS);
  scale_bias_act<<<(NA * HID / 4 + 255) / 256, 256, 0, stream>>>(ha0, lin_a_b, NA * HID / 4, 1.f, 1);
  scale_bias_act<<<(NB * HID / 4 + 255) / 256, 256, 0, stream>>>(hb0, lin_b_b, NB * HID / 4, 1.f, 1);

  auto run_gat = [&](int g, const float* hsrcF, int nsrc, const float* hdstF, int ndst,
                     const int* indptr, const int* srcs, const float* bias,
                     float* outp, int relu) {
    const float* vs_ = vv + (size_t)(2 * g) * HID * HEADS;
    const float* vd_ = vv + (size_t)(2 * g + 1) * HID * HEADS;
    const float* Wp = Wp4 + (size_t)g * HEADS * HID * HID;
    compute_al2<<<((nsrc + ndst) * HEADS + 255) / 256, 256, 0, stream>>>(
        hsrcF, hdstF, vs_, vd_, al_s, al_d, nsrc, ndst);
    gat_edge<<<ndst, 128, 0, stream>>>(indptr, srcs, al_s, al_d, hsrcF, z, ndst);
    gemm_splitk<<<dim3(HID / 64, (ndst + 63) / 64, KS), 256, 0, stream>>>(
        z, Wp, outp, ndst, HID, HEADS * HID, (HEADS * HID) / KS);
    scale_bias_act<<<(ndst * HID / 4 + 255) / 256, 256, 0, stream>>>(
        outp, bias, ndst * HID / 4, 1.f / HEADS, relu);
  };

  // layer 1
  run_gat(0, ha0, NA, hb0, NB, indptr_ab, srcs_ab, (const float*)d_in[16], hb1, 1);
  run_gat(1, hb0, NB, ha0, NA, indptr_ba, srcs_ba, (const float*)d_in[21], ha1, 1);
  // layer 2
  run_gat(2, ha1, NA, hb1, NB, indptr_ab, srcs_ab, (const float*)d_in[26], hb2, 0);
  run_gat(3, hb1, NB, ha1, NA, indptr_ba, srcs_ba, (const float*)d_in[31], ha2, 0);

  // pooled mean + FC
  pool_dot2<<<320, 256, 0, stream>>>(ha2, hb2, batch_a, batch_b, fc_w, gsum, NA, NB);
  finalize_out<<<1, 64, 0, stream>>>(gsum, batch_a, batch_b, fc_b,
                                     (float*)d_out, NA, NB, NG);
}

// Round 4
// 489.962 us; speedup vs baseline: 1.6108x; 1.6108x over previous
//
#include <hip/hip_runtime.h>
#include <math.h>

#define HID 128
#define HEADS 8
#define MAXE 128

// ================= dual-segment split-K GEMM, N=128, partial-buffer output =================
// Segment picked by blockIdx.y. Partial P[z][rowbase+row][0:128] written with plain stores.
struct GSeg { const float* A; const float* B; int M; int K; int yb; };

__global__ __launch_bounds__(256) void gemm2_splitk(
    GSeg s0, GSeg s1, float* __restrict__ P, int Mtot, int KS)
{
  __shared__ float As[16][68];  // [k][m], padded
  __shared__ float Bs[16][68];  // [k][n], padded
  const int tid = threadIdx.x;
  const float* A; const float* B; int M, K, rowbase, ylocal;
  if ((int)blockIdx.y < s0.yb) {
    A = s0.A; B = s0.B; M = s0.M; K = s0.K; rowbase = 0; ylocal = blockIdx.y;
  } else {
    A = s1.A; B = s1.B; M = s1.M; K = s1.K; rowbase = s0.yb * 64; ylocal = blockIdx.y - s0.yb;
  }
  const int bm = ylocal * 64;
  const int bn = blockIdx.x * 64;
  const int kchunk = K / KS;
  const int kbeg = blockIdx.z * kchunk;
  const int kend = kbeg + kchunk;
  const int tx = tid & 15, ty = tid >> 4;
  const int a_row = tid >> 2, a_col = (tid & 3) << 2;
  const int b_row = tid >> 4, b_col = (tid & 15) << 2;
  float acc[4][4];
#pragma unroll
  for (int i = 0; i < 4; i++)
#pragma unroll
    for (int j = 0; j < 4; j++) acc[i][j] = 0.f;

  const int gr = bm + a_row;
  for (int k0 = kbeg; k0 < kend; k0 += 16) {
    float4 av = make_float4(0.f, 0.f, 0.f, 0.f);
    if (gr < M) av = *(const float4*)(A + (size_t)gr * K + (k0 + a_col));
    As[a_col + 0][a_row] = av.x;
    As[a_col + 1][a_row] = av.y;
    As[a_col + 2][a_row] = av.z;
    As[a_col + 3][a_row] = av.w;
    float4 bv = *(const float4*)(B + (size_t)(k0 + b_row) * HID + (bn + b_col));
    *(float4*)&Bs[b_row][b_col] = bv;
    __syncthreads();
#pragma unroll
    for (int kk = 0; kk < 16; kk++) {
      float4 a4 = *(const float4*)&As[kk][ty << 2];
      float4 b4 = *(const float4*)&Bs[kk][tx << 2];
      float ar[4] = {a4.x, a4.y, a4.z, a4.w};
      float br[4] = {b4.x, b4.y, b4.z, b4.w};
#pragma unroll
      for (int i = 0; i < 4; i++)
#pragma unroll
        for (int j = 0; j < 4; j++) acc[i][j] = fmaf(ar[i], br[j], acc[i][j]);
    }
    __syncthreads();
  }
  const size_t prow = (size_t)blockIdx.z * Mtot + rowbase + bm;
#pragma unroll
  for (int i = 0; i < 4; i++) {
    float* pp = P + (prow + (ty << 2) + i) * HID + bn + (tx << 2);
    float4 o = make_float4(acc[i][0], acc[i][1], acc[i][2], acc[i][3]);
    *(float4*)pp = o;
  }
}

// ================= reduce KS partials + scale + bias + act, route rows to 2 outputs ========
struct RSeg { float* out; const float* bias; int M; int rowbase; };

__global__ __launch_bounds__(256) void reduce_epi(
    const float* __restrict__ P, int Mtot, int KS, float scale, int do_relu,
    RSeg s0, RSeg s1)
{
  int idx = blockIdx.x * 256 + threadIdx.x;  // one float4
  if (idx >= Mtot * 32) return;
  int r = idx >> 5;
  int c = (idx & 31) << 2;
  float* outp; const float* bias; int rl;
  if (s1.M > 0 && r >= s1.rowbase) {
    rl = r - s1.rowbase; if (rl >= s1.M) return; outp = s1.out; bias = s1.bias;
  } else {
    rl = r; if (rl >= s0.M) return; outp = s0.out; bias = s0.bias;
  }
  float4 acc = make_float4(0.f, 0.f, 0.f, 0.f);
  for (int z = 0; z < KS; z++) {
    const float4 v = *(const float4*)(P + ((size_t)z * Mtot + r) * HID + c);
    acc.x += v.x; acc.y += v.y; acc.z += v.z; acc.w += v.w;
  }
  const float4 b = *(const float4*)(bias + c);
  acc.x = acc.x * scale + b.x;
  acc.y = acc.y * scale + b.y;
  acc.z = acc.z * scale + b.z;
  acc.w = acc.w * scale + b.w;
  if (do_relu) {
    acc.x = acc.x > 0.f ? acc.x : 0.f;
    acc.y = acc.y > 0.f ? acc.y : 0.f;
    acc.z = acc.z > 0.f ? acc.z : 0.f;
    acc.w = acc.w > 0.f ? acc.w : 0.f;
  }
  *(float4*)(outp + (size_t)rl * HID + c) = acc;
}

// ================= upfront weight prep: 4x permute + 8x make_v =================
struct PrepArgs {
  const float* W[8];   // s_ab, d_ab, s_ba, d_ba (L1), then L2
  const float* a[8];
  float* Wp[4];
  float* v[8];
};

__global__ __launch_bounds__(256) void prep_weights(PrepArgs p)
{
  int bid = blockIdx.x;
  if (bid < 2048) {  // permute: Wp[g][(h*128+k)*128+c] = Ws[g][k*1024+h*128+c]
    int g = bid >> 9;
    int idx = ((bid & 511) << 8) + threadIdx.x;
    int c = idx & (HID - 1);
    int kk = idx >> 7;
    int h = kk >> 7, k = kk & (HID - 1);
    p.Wp[g][idx] = p.W[2 * g][(size_t)k * (HEADS * HID) + h * HID + c];
  } else {           // make_v: v[wi][k*8+h] = sum_c W[wi][k, h*128+c] * a[wi][h,c]
    int u = bid - 2048;
    int wi = u >> 2;
    int gid = ((u & 3) << 8) + threadIdx.x;
    int k = gid >> 3, h = gid & 7;
    const float* wr = p.W[wi] + (size_t)k * (HEADS * HID) + h * HID;
    const float* ar = p.a[wi] + (size_t)h * HID;
    float s = 0.f;
    for (int c = 0; c < HID; c++) s = fmaf(wr[c], ar[c], s);
    p.v[wi][gid] = s;
  }
}

// ================= 4 attention-logit arrays per layer in one launch =================
__global__ __launch_bounds__(256) void compute_al4(
    const float* __restrict__ ha, const float* __restrict__ hb,
    const float* __restrict__ v4,
    float* __restrict__ o0, float* __restrict__ o1,
    float* __restrict__ o2, float* __restrict__ o3, int na, int nb)
{
  __shared__ float vsh[4 * HID * HEADS];  // 16 KB
  for (int i = threadIdx.x; i < 4 * HID * HEADS; i += 256) vsh[i] = v4[i];
  __syncthreads();
  int gid = blockIdx.x * 256 + threadIdx.x;
  int row = gid >> 3, h = gid & 7;
  const float* hr; float* o; int q, rl;
  if (row < na)                    { q = 0; rl = row;                 hr = ha; o = o0; }
  else if (row < na + nb)          { q = 1; rl = row - na;            hr = hb; o = o1; }
  else if (row < na + 2 * nb)      { q = 2; rl = row - na - nb;       hr = hb; o = o2; }
  else if (row < 2 * na + 2 * nb)  { q = 3; rl = row - na - 2 * nb;   hr = ha; o = o3; }
  else return;
  hr += (size_t)rl * HID;
  const float* vq = vsh + q * HID * HEADS;
  float s = 0.f;
  for (int k = 0; k < HID; k++) s = fmaf(hr[k], vq[k * HEADS + h], s);
  o[(size_t)rl * HEADS + h] = s;
}

// ================= CSR build (both directions fused) =================
__global__ __launch_bounds__(256) void hist2(
    const int* __restrict__ dst_ab, const int* __restrict__ dst_ba,
    int* __restrict__ cnt_ab, int* __restrict__ cnt_ba, int E)
{
  int gid = blockIdx.x * 256 + threadIdx.x;
  if (gid < E) atomicAdd(&cnt_ab[dst_ab[gid]], 1);
  else if (gid < 2 * E) atomicAdd(&cnt_ba[dst_ba[gid - E]], 1);
}

__global__ __launch_bounds__(1024) void scan2(
    const int* __restrict__ cnt_ab, const int* __restrict__ cnt_ba,
    int* __restrict__ ip_ab, int* __restrict__ ip_ba, int n_ab, int n_ba)
{
  const int* cnt = (blockIdx.x == 0) ? cnt_ab : cnt_ba;
  int* indptr = (blockIdx.x == 0) ? ip_ab : ip_ba;
  int n = (blockIdx.x == 0) ? n_ab : n_ba;
  __shared__ int parts[1024];
  const int tid = threadIdx.x;
  const int base = tid * 10;
  int local[10];
  int s = 0;
#pragma unroll
  for (int j = 0; j < 10; j++) {
    int v = (base + j < n) ? cnt[base + j] : 0;
    local[j] = v; s += v;
  }
  parts[tid] = s;
  __syncthreads();
  for (int off = 1; off < 1024; off <<= 1) {
    int v = (tid >= off) ? parts[tid - off] : 0;
    __syncthreads();
    parts[tid] += v;
    __syncthreads();
  }
  int ex = parts[tid] - s;
#pragma unroll
  for (int j = 0; j < 10; j++) {
    if (base + j < n) indptr[base + j] = ex;
    ex += local[j];
  }
  if (tid == 1023) indptr[n] = parts[1023];
}

__global__ __launch_bounds__(256) void scatter2(
    const int* __restrict__ edge_ab, const int* __restrict__ edge_ba,
    const int* __restrict__ ip_ab, const int* __restrict__ ip_ba,
    int* __restrict__ cur_ab, int* __restrict__ cur_ba,
    int* __restrict__ srcs_ab, int* __restrict__ srcs_ba, int E)
{
  int gid = blockIdx.x * 256 + threadIdx.x;
  if (gid < E) {
    int d = edge_ab[E + gid];
    int pos = ip_ab[d] + atomicAdd(&cur_ab[d], 1);
    srcs_ab[pos] = edge_ab[gid];
  } else if (gid < 2 * E) {
    int g = gid - E;
    int d = edge_ba[E + g];
    int pos = ip_ba[d] + atomicAdd(&cur_ba[d], 1);
    srcs_ba[pos] = edge_ba[g];
  }
}

// ================= per-dst segment softmax + aggregation (dual-direction) =================
struct GDir {
  const int* indptr; const int* srcs;
  const float* als; const float* ald;
  const float* h; float* z;
};

__global__ __launch_bounds__(128) void gat_edge2(GDir d0, GDir d1, int n0)
{
  const bool first = ((int)blockIdx.x < n0);
  const int* indptr = first ? d0.indptr : d1.indptr;
  const int* srcs   = first ? d0.srcs   : d1.srcs;
  const float* als  = first ? d0.als    : d1.als;
  const float* ald  = first ? d0.ald    : d1.ald;
  const float* hsrc = first ? d0.h      : d1.h;
  float* z          = first ? d0.z      : d1.z;
  const int n = first ? blockIdx.x : blockIdx.x - n0;

  const int tid = threadIdx.x;
  __shared__ unsigned mu[HEADS];
  __shared__ float mf[HEADS], den[HEADS], aldn[HEADS];
  __shared__ float lw[MAXE][HEADS];
  __shared__ int es[MAXE];
  const int base = indptr[n];
  const int deg = indptr[n + 1] - base;
  if (tid < HEADS) {
    mu[tid] = 0u;
    den[tid] = 0.f;
    aldn[tid] = ald[(size_t)n * HEADS + tid];
  }
  const bool fast = (deg <= MAXE);
  if (fast)
    for (int i = tid; i < deg; i += 128) es[i] = srcs[base + i];
  __syncthreads();

  float acc[HEADS];
#pragma unroll
  for (int h = 0; h < HEADS; h++) acc[h] = 0.f;

  if (fast) {
    const int tot = deg * HEADS;
    for (int i = tid; i < tot; i += 128) {
      int e = i >> 3, h = i & 7;
      float v = als[(size_t)es[e] * HEADS + h] + aldn[h];
      v = v > 0.f ? v : 0.2f * v;
      lw[e][h] = v;
      unsigned u = __float_as_uint(v);
      u = (u & 0x80000000u) ? ~u : (u | 0x80000000u);
      atomicMax(&mu[h], u);
    }
    __syncthreads();
    if (tid < HEADS) {
      unsigned u = mu[tid];
      mf[tid] = __uint_as_float((u & 0x80000000u) ? (u ^ 0x80000000u) : ~u);
    }
    __syncthreads();
    for (int i = tid; i < tot; i += 128) {
      int e = i >> 3, h = i & 7;
      float ex = expf(lw[e][h] - mf[h]);
      lw[e][h] = ex;
      atomicAdd(&den[h], ex);
    }
    __syncthreads();
    for (int i = tid; i < tot; i += 128) {
      int e = i >> 3, h = i & 7;
      lw[e][h] = lw[e][h] / (den[h] + 1e-16f);
    }
    __syncthreads();
    for (int e = 0; e < deg; e++) {
      float hv = hsrc[(size_t)es[e] * HID + tid];
#pragma unroll
      for (int h = 0; h < HEADS; h++) acc[h] = fmaf(lw[e][h], hv, acc[h]);
    }
  } else {
    const int tot = deg * HEADS;
    for (int i = tid; i < tot; i += 128) {
      int e = i >> 3, h = i & 7;
      float v = als[(size_t)srcs[base + e] * HEADS + h] + aldn[h];
      v = v > 0.f ? v : 0.2f * v;
      unsigned u = __float_as_uint(v);
      u = (u & 0x80000000u) ? ~u : (u | 0x80000000u);
      atomicMax(&mu[h], u);
    }
    __syncthreads();
    if (tid < HEADS) {
      unsigned u = mu[tid];
      mf[tid] = __uint_as_float((u & 0x80000000u) ? (u ^ 0x80000000u) : ~u);
    }
    __syncthreads();
    for (int i = tid; i < tot; i += 128) {
      int e = i >> 3, h = i & 7;
      float v = als[(size_t)srcs[base + e] * HEADS + h] + aldn[h];
      v = v > 0.f ? v : 0.2f * v;
      atomicAdd(&den[h], expf(v - mf[h]));
    }
    __syncthreads();
    for (int e0 = 0; e0 < deg; e0 += MAXE) {
      int ne = deg - e0; if (ne > MAXE) ne = MAXE;
      for (int i = tid; i < ne; i += 128) es[i] = srcs[base + e0 + i];
      __syncthreads();
      for (int i = tid; i < ne * HEADS; i += 128) {
        int e = i >> 3, h = i & 7;
        float v = als[(size_t)es[e] * HEADS + h] + aldn[h];
        v = v > 0.f ? v : 0.2f * v;
        lw[e][h] = expf(v - mf[h]) / (den[h] + 1e-16f);
      }
      __syncthreads();
      for (int e = 0; e < ne; e++) {
        float hv = hsrc[(size_t)es[e] * HID + tid];
#pragma unroll
        for (int h = 0; h < HEADS; h++) acc[h] = fmaf(lw[e][h], hv, acc[h]);
      }
      __syncthreads();
    }
  }
  float* zp = z + (size_t)n * (HEADS * HID) + tid;
#pragma unroll
  for (int h = 0; h < HEADS; h++) zp[h * HID] = acc[h];
}

// ================= pool + FC =================
__global__ __launch_bounds__(256) void pool_dot2(
    const float* __restrict__ ha, const float* __restrict__ hb,
    const int* __restrict__ batch_a, const int* __restrict__ batch_b,
    const float* __restrict__ fc_w, float* __restrict__ gsum, int na, int nb)
{
  const bool isA = blockIdx.x < 160;
  const float* h = isA ? ha : hb;
  const int* batch = isA ? batch_a : batch_b;
  const float* wseg = isA ? fc_w : fc_w + HID;
  float* gs = isA ? gsum : gsum + 8;
  const int n = isA ? na : nb;
  const int b = isA ? blockIdx.x : blockIdx.x - 160;

  __shared__ float sg[8];
  if (threadIdx.x < 8) sg[threadIdx.x] = 0.f;
  __syncthreads();
  const int lane = threadIdx.x & 63;
  const int wv = threadIdx.x >> 6;
  const int gw = b * 4 + wv;
  const int tw = 160 * 4;
  const float2 w2 = *(const float2*)(wseg + lane * 2);
  for (int r = gw; r < n; r += tw) {
    float2 hv = *(const float2*)(h + (size_t)r * HID + lane * 2);
    float s = hv.x * w2.x + hv.y * w2.y;
#pragma unroll
    for (int off = 32; off > 0; off >>= 1) s += __shfl_down(s, off, 64);
    if (lane == 0) atomicAdd(&sg[batch[r]], s);
  }
  __syncthreads();
  if (threadIdx.x < 8) atomicAdd(&gs[threadIdx.x], sg[threadIdx.x]);
}

__global__ __launch_bounds__(64) void finalize_out(
    const float* __restrict__ gsum, const int* __restrict__ batch_a,
    const int* __restrict__ batch_b, const float* __restrict__ fc_b,
    float* __restrict__ out, int na, int nb, int ng)
{
  int g = threadIdx.x;
  if (g >= ng) return;
  int l, r, lo;
  l = 0; r = na; while (l < r) { int m = (l + r) >> 1; if (batch_a[m] < g) l = m + 1; else r = m; } lo = l;
  r = na; while (l < r) { int m = (l + r) >> 1; if (batch_a[m] < g + 1) l = m + 1; else r = m; }
  int ca = l - lo; if (ca < 1) ca = 1;
  l = 0; r = nb; while (l < r) { int m = (l + r) >> 1; if (batch_b[m] < g) l = m + 1; else r = m; } lo = l;
  r = nb; while (l < r) { int m = (l + r) >> 1; if (batch_b[m] < g + 1) l = m + 1; else r = m; }
  int cb = l - lo; if (cb < 1) cb = 1;
  out[g] = gsum[g] / (float)ca + gsum[8 + g] / (float)cb + fc_b[0];
}

extern "C" void kernel_launch(void* const* d_in, const int* in_sizes, int n_in,
                              void* d_out, int out_size, void* d_ws, size_t ws_size,
                              hipStream_t stream)
{
  const float* x_a = (const float*)d_in[0];
  const float* x_b = (const float*)d_in[1];
  const int* edge_ab = (const int*)d_in[2];
  const int* edge_ba = (const int*)d_in[3];
  const int* batch_a = (const int*)d_in[4];
  const int* batch_b = (const int*)d_in[5];
  const float* lin_a_w = (const float*)d_in[6];
  const float* lin_a_b = (const float*)d_in[7];
  const float* lin_b_w = (const float*)d_in[8];
  const float* lin_b_b = (const float*)d_in[9];
  const float* fc_w = (const float*)d_in[10];
  const float* fc_b = (const float*)d_in[11];

  const int NA = in_sizes[4];
  const int NB = in_sizes[5];
  const int E  = in_sizes[2] / 2;
  const int FA = in_sizes[0] / NA;
  const int FB = in_sizes[1] / NB;
  const int NG = out_size;
  const int NMAX = NA > NB ? NA : NB;
  const int NAp = (NA + 63) & ~63, NBp = (NB + 63) & ~63;
  const int yba = NAp / 64, ybb = NBp / 64;
  const int Mtot = NAp + NBp;

  // ---- size model (mirrors carve order; 256B-align each, + margin) ----
  auto al256 = [](size_t b) { return (b + 255) & ~(size_t)255; };
  size_t fixed = 0;
  fixed += 3 * al256((size_t)NAp * HID * 4) + 3 * al256((size_t)NBp * HID * 4);  // ha0..2, hb0..2
  fixed += al256((size_t)NBp * HEADS * HID * 4);                                  // z_ab
  fixed += al256((size_t)4 * HEADS * HID * HID * 4);                              // Wp4
  fixed += al256((size_t)8 * HID * HEADS * 4);                                    // vv
  fixed += 2 * al256((size_t)NAp * HEADS * 4) + 2 * al256((size_t)NBp * HEADS * 4); // al arrays
  fixed += al256(((size_t)4 * NMAX + 16) * 4);                                    // csr cnt/cur + gsum
  fixed += al256((size_t)(NB + 1) * 4) + al256((size_t)(NA + 1) * 4);             // indptrs
  fixed += 2 * al256((size_t)E * 4);                                              // srcs
  fixed += 8192;                                                                  // margin
  const size_t zba_sz = al256((size_t)NAp * HEADS * HID * 4);
  const size_t pslice = al256((size_t)Mtot * HID * 4);

  int KS = 4; bool dual = true;
  if (fixed + zba_sz + 4 * pslice <= ws_size)      { dual = true;  KS = 4; }
  else if (fixed + zba_sz + 2 * pslice <= ws_size) { dual = true;  KS = 2; }
  else if (fixed + 4 * pslice <= ws_size)          { dual = false; KS = 4; }
  else if (fixed + 2 * pslice <= ws_size)          { dual = false; KS = 2; }
  else if (fixed + 1 * pslice <= ws_size)          { dual = false; KS = 1; }
  else return;  // loud failure (out stays poisoned)

  char* w = (char*)d_ws;
  auto carve = [&](size_t bytes) -> void* {
    void* p = (void*)w;
    w += (bytes + 255) & ~(size_t)255;
    return p;
  };
  float* ha0 = (float*)carve((size_t)NAp * HID * 4);
  float* hb0 = (float*)carve((size_t)NBp * HID * 4);
  float* ha1 = (float*)carve((size_t)NAp * HID * 4);
  float* hb1 = (float*)carve((size_t)NBp * HID * 4);
  float* ha2 = (float*)carve((size_t)NAp * HID * 4);
  float* hb2 = (float*)carve((size_t)NBp * HID * 4);
  float* z_ab = (float*)carve((size_t)NBp * HEADS * HID * 4);
  float* z_ba = dual ? (float*)carve((size_t)NAp * HEADS * HID * 4) : z_ab;
  float* P    = (float*)carve((size_t)KS * Mtot * HID * 4);
  float* Wp4  = (float*)carve((size_t)4 * HEADS * HID * HID * 4);
  float* vv   = (float*)carve((size_t)8 * HID * HEADS * 4);
  float* als_ab = (float*)carve((size_t)NAp * HEADS * 4);
  float* ald_ab = (float*)carve((size_t)NBp * HEADS * 4);
  float* als_ba = (float*)carve((size_t)NBp * HEADS * 4);
  float* ald_ba = (float*)carve((size_t)NAp * HEADS * 4);
  int* csrblk = (int*)carve(((size_t)4 * NMAX + 16) * 4);
  int* indptr_ab = (int*)carve((size_t)(NB + 1) * 4);
  int* indptr_ba = (int*)carve((size_t)(NA + 1) * 4);
  int* srcs_ab   = (int*)carve((size_t)E * 4);
  int* srcs_ba   = (int*)carve((size_t)E * 4);
  if ((size_t)(w - (char*)d_ws) > ws_size) return;

  int* cnt_ab = csrblk;
  int* cnt_ba = csrblk + NMAX;
  int* cur_ab = csrblk + 2 * NMAX;
  int* cur_ba = csrblk + 3 * NMAX;
  float* gsum = (float*)(csrblk + 4 * NMAX);

  hipMemsetAsync(csrblk, 0, ((size_t)4 * NMAX + 16) * 4, stream);

  // ---- weight prep ----
  PrepArgs pa;
  const int wi_idx[8] = {12, 13, 17, 18, 22, 23, 27, 28};
  const int ai_idx[8] = {14, 15, 19, 20, 24, 25, 29, 30};
  for (int i = 0; i < 8; i++) {
    pa.W[i] = (const float*)d_in[wi_idx[i]];
    pa.a[i] = (const float*)d_in[ai_idx[i]];
    pa.v[i] = vv + (size_t)i * HID * HEADS;
  }
  for (int g = 0; g < 4; g++) pa.Wp[g] = Wp4 + (size_t)g * HEADS * HID * HID;
  prep_weights<<<2048 + 32, 256, 0, stream>>>(pa);

  // ---- CSR both directions ----
  hist2<<<(2 * E + 255) / 256, 256, 0, stream>>>(edge_ab + E, edge_ba + E, cnt_ab, cnt_ba, E);
  scan2<<<2, 1024, 0, stream>>>(cnt_ab, cnt_ba, indptr_ab, indptr_ba, NB, NA);
  scatter2<<<(2 * E + 255) / 256, 256, 0, stream>>>(
      edge_ab, edge_ba, indptr_ab, indptr_ba, cur_ab, cur_ba, srcs_ab, srcs_ba, E);

  const int red_grid = (Mtot * 32 + 255) / 256;
  const GSeg gnone = {nullptr, nullptr, 0, 16, 0};
  const RSeg rnone = {nullptr, nullptr, 0, 0};

  // ---- input linears: both in ONE dual-segment split-K launch ----
  {
    GSeg sa = {x_a, lin_a_w, NA, FA, yba};
    GSeg sb = {x_b, lin_b_w, NB, FB, ybb};
    gemm2_splitk<<<dim3(2, yba + ybb, KS), 256, 0, stream>>>(sa, sb, P, Mtot, KS);
    RSeg ra = {ha0, lin_a_b, NA, 0};
    RSeg rb = {hb0, lin_b_b, NB, yba * 64};
    reduce_epi<<<red_grid, 256, 0, stream>>>(P, Mtot, KS, 1.f, 1, ra, rb);
  }

  // ---- two GAT layers ----
  auto run_layer = [&](int L, const float* haP, const float* hbP,
                       float* haN, float* hbN, const float* b_ab, const float* b_ba,
                       int relu) {
    compute_al4<<<((2 * (NA + NB)) * HEADS + 255) / 256, 256, 0, stream>>>(
        haP, hbP, vv + (size_t)L * 4 * HID * HEADS,
        als_ab, ald_ab, als_ba, ald_ba, NA, NB);
    GDir dab = {indptr_ab, srcs_ab, als_ab, ald_ab, haP, z_ab};
    GDir dba = {indptr_ba, srcs_ba, als_ba, ald_ba, hbP, z_ba};
    const float* Wab = Wp4 + (size_t)(2 * L) * HEADS * HID * HID;
    const float* Wba = Wp4 + (size_t)(2 * L + 1) * HEADS * HID * HID;
    if (dual) {
      gat_edge2<<<NB + NA, 128, 0, stream>>>(dab, dba, NB);
      GSeg s0 = {z_ab, Wab, NB, HEADS * HID, ybb};
      GSeg s1 = {z_ba, Wba, NA, HEADS * HID, yba};
      gemm2_splitk<<<dim3(2, ybb + yba, KS), 256, 0, stream>>>(s0, s1, P, Mtot, KS);
      RSeg r0 = {hbN, b_ab, NB, 0};
      RSeg r1 = {haN, b_ba, NA, ybb * 64};
      reduce_epi<<<red_grid, 256, 0, stream>>>(P, Mtot, KS, 1.f / HEADS, relu, r0, r1);
    } else {
      // shared z buffer: serialize directions
      gat_edge2<<<NB, 128, 0, stream>>>(dab, dab, NB);
      GSeg s0 = {z_ab, Wab, NB, HEADS * HID, ybb};
      gemm2_splitk<<<dim3(2, ybb, KS), 256, 0, stream>>>(s0, gnone, P, NBp, KS);
      RSeg r0 = {hbN, b_ab, NB, 0};
      reduce_epi<<<(NBp * 32 + 255) / 256, 256, 0, stream>>>(P, NBp, KS, 1.f / HEADS, relu, r0, rnone);
      gat_edge2<<<NA, 128, 0, stream>>>(dba, dba, NA);
      GSeg s1 = {z_ba, Wba, NA, HEADS * HID, yba};
      gemm2_splitk<<<dim3(2, yba, KS), 256, 0, stream>>>(s1, gnone, P, NAp, KS);
      RSeg r1 = {haN, b_ba, NA, 0};
      reduce_epi<<<(NAp * 32 + 255) / 256, 256, 0, stream>>>(P, NAp, KS, 1.f / HEADS, relu, r1, rnone);
    }
  };

  run_layer(0, ha0, hb0, ha1, hb1, (const float*)d_in[16], (const float*)d_in[21], 1);
  run_layer(1, ha1, hb1, ha2, hb2, (const float*)d_in[26], (const float*)d_in[31], 0);

  // ---- pooled mean + FC ----
  pool_dot2<<<320, 256, 0, stream>>>(ha2, hb2, batch_a, batch_b, fc_w, gsum, NA, NB);
  finalize_out<<<1, 64, 0, stream>>>(gsum, batch_a, batch_b, fc_b,
                                     (float*)d_out, NA, NB, NG);
}

// Round 5
// 484.035 us; speedup vs baseline: 1.6305x; 1.0122x over previous
//
#include <hip/hip_runtime.h>
#include <math.h>

#define HID 128
#define HEADS 8

// ================= dual-segment split-K GEMM, N=128, 128x128 tile, 8x8/thread =================
// blockIdx.x = row-tile (segment-select), blockIdx.y = K-slice. Partials to P, plain stores.
struct GSeg { const float* A; const float* B; int M; int K; int yb; };  // yb = #128-row tiles

__global__ __launch_bounds__(256, 3) void gemm2_splitk(
    GSeg s0, GSeg s1, float* __restrict__ P, int Mtot, int KS)
{
  __shared__ float As[16][132];  // [k][m]
  __shared__ float Bs[16][132];  // [k][n]
  const int tid = threadIdx.x;
  const float* A; const float* B; int M, K, rowbase, ytile;
  if ((int)blockIdx.x < s0.yb) {
    A = s0.A; B = s0.B; M = s0.M; K = s0.K; rowbase = 0; ytile = blockIdx.x;
  } else {
    A = s1.A; B = s1.B; M = s1.M; K = s1.K; rowbase = s0.yb * 128; ytile = blockIdx.x - s0.yb;
  }
  const int bm = ytile * 128;
  const int kchunk = K / KS;
  const int kbeg = blockIdx.y * kchunk;

  const int am = tid >> 1;          // 0..127
  const int ak = (tid & 1) << 3;    // 0 or 8
  const int brr = tid >> 4;         // 0..15
  const int bcc = (tid & 15) << 2;  // 0..60
  const int tx = tid & 15, ty = tid >> 4;

  float acc[64];
#pragma unroll
  for (int i = 0; i < 64; i++) acc[i] = 0.f;

  const int gr = bm + am;
  const float* Arow = A + (size_t)gr * K;
  for (int k0 = kbeg; k0 < kbeg + kchunk; k0 += 16) {
    float4 av0 = make_float4(0.f, 0.f, 0.f, 0.f), av1 = av0;
    if (gr < M) {
      av0 = *(const float4*)(Arow + k0 + ak);
      av1 = *(const float4*)(Arow + k0 + ak + 4);
    }
    const float4 bv0 = *(const float4*)(B + (size_t)(k0 + brr) * HID + bcc);
    const float4 bv1 = *(const float4*)(B + (size_t)(k0 + brr) * HID + bcc + 64);
    As[ak + 0][am] = av0.x; As[ak + 1][am] = av0.y;
    As[ak + 2][am] = av0.z; As[ak + 3][am] = av0.w;
    As[ak + 4][am] = av1.x; As[ak + 5][am] = av1.y;
    As[ak + 6][am] = av1.z; As[ak + 7][am] = av1.w;
    *(float4*)&Bs[brr][bcc] = bv0;
    *(float4*)&Bs[brr][bcc + 64] = bv1;
    __syncthreads();
#pragma unroll
    for (int kk = 0; kk < 16; kk++) {
      const float4 a0 = *(const float4*)&As[kk][ty << 3];
      const float4 a1 = *(const float4*)&As[kk][(ty << 3) + 4];
      const float4 b0 = *(const float4*)&Bs[kk][tx << 3];
      const float4 b1 = *(const float4*)&Bs[kk][(tx << 3) + 4];
      const float ar[8] = {a0.x, a0.y, a0.z, a0.w, a1.x, a1.y, a1.z, a1.w};
      const float bq[8] = {b0.x, b0.y, b0.z, b0.w, b1.x, b1.y, b1.z, b1.w};
#pragma unroll
      for (int i = 0; i < 8; i++)
#pragma unroll
        for (int j = 0; j < 8; j++) acc[i * 8 + j] = fmaf(ar[i], bq[j], acc[i * 8 + j]);
    }
    __syncthreads();
  }
  const size_t prow0 = (size_t)blockIdx.y * Mtot + rowbase + bm;
#pragma unroll
  for (int i = 0; i < 8; i++) {
    float* pp = P + (prow0 + (ty << 3) + i) * HID + (tx << 3);
    *(float4*)pp       = make_float4(acc[i * 8 + 0], acc[i * 8 + 1], acc[i * 8 + 2], acc[i * 8 + 3]);
    *(float4*)(pp + 4) = make_float4(acc[i * 8 + 4], acc[i * 8 + 5], acc[i * 8 + 6], acc[i * 8 + 7]);
  }
}

// ================= reduce KS partials + scale + bias + act, route rows to 2 outputs ========
struct RSeg { float* out; const float* bias; int M; int rowbase; };

__global__ __launch_bounds__(256) void reduce_epi(
    const float* __restrict__ P, int Mtot, int KS, float scale, int do_relu,
    RSeg s0, RSeg s1)
{
  int idx = blockIdx.x * 256 + threadIdx.x;  // one float4
  if (idx >= Mtot * 32) return;
  int r = idx >> 5;
  int c = (idx & 31) << 2;
  float* outp; const float* bias; int rl;
  if (s1.M > 0 && r >= s1.rowbase) {
    rl = r - s1.rowbase; if (rl >= s1.M) return; outp = s1.out; bias = s1.bias;
  } else {
    rl = r; if (rl >= s0.M) return; outp = s0.out; bias = s0.bias;
  }
  float4 acc = make_float4(0.f, 0.f, 0.f, 0.f);
  for (int z = 0; z < KS; z++) {
    const float4 v = *(const float4*)(P + ((size_t)z * Mtot + r) * HID + c);
    acc.x += v.x; acc.y += v.y; acc.z += v.z; acc.w += v.w;
  }
  const float4 b = *(const float4*)(bias + c);
  acc.x = acc.x * scale + b.x;
  acc.y = acc.y * scale + b.y;
  acc.z = acc.z * scale + b.z;
  acc.w = acc.w * scale + b.w;
  if (do_relu) {
    acc.x = acc.x > 0.f ? acc.x : 0.f;
    acc.y = acc.y > 0.f ? acc.y : 0.f;
    acc.z = acc.z > 0.f ? acc.z : 0.f;
    acc.w = acc.w > 0.f ? acc.w : 0.f;
  }
  *(float4*)(outp + (size_t)rl * HID + c) = acc;
}

// ================= upfront weight prep: 4x permute + 8x make_v =================
struct PrepArgs {
  const float* W[8];
  const float* a[8];
  float* Wp[4];
  float* v[8];
};

__global__ __launch_bounds__(256) void prep_weights(PrepArgs p)
{
  int bid = blockIdx.x;
  if (bid < 2048) {  // Wp[g][(h*128+k)*128+c] = Ws[g][k*1024+h*128+c]
    int g = bid >> 9;
    int idx = ((bid & 511) << 8) + threadIdx.x;
    int c = idx & (HID - 1);
    int kk = idx >> 7;
    int h = kk >> 7, k = kk & (HID - 1);
    p.Wp[g][idx] = p.W[2 * g][(size_t)k * (HEADS * HID) + h * HID + c];
  } else {           // v[wi][k*8+h] = sum_c W[wi][k, h*128+c] * a[wi][h,c]
    int u = bid - 2048;
    int wi = u >> 2;
    int gid = ((u & 3) << 8) + threadIdx.x;
    int k = gid >> 3, h = gid & 7;
    const float* wr = p.W[wi] + (size_t)k * (HEADS * HID) + h * HID;
    const float* ar = p.a[wi] + (size_t)h * HID;
    float s = 0.f;
    for (int c = 0; c < HID; c++) s = fmaf(wr[c], ar[c], s);
    p.v[wi][gid] = s;
  }
}

// ================= 4 attention-logit arrays per layer in one launch =================
__global__ __launch_bounds__(256) void compute_al4(
    const float* __restrict__ ha, const float* __restrict__ hb,
    const float* __restrict__ v4,
    float* __restrict__ o0, float* __restrict__ o1,
    float* __restrict__ o2, float* __restrict__ o3, int na, int nb)
{
  __shared__ float vsh[4 * HID * HEADS];
  for (int i = threadIdx.x; i < 4 * HID * HEADS; i += 256) vsh[i] = v4[i];
  __syncthreads();
  int gid = blockIdx.x * 256 + threadIdx.x;
  int row = gid >> 3, h = gid & 7;
  const float* hr; float* o; int q, rl;
  if (row < na)                    { q = 0; rl = row;               hr = ha; o = o0; }
  else if (row < na + nb)          { q = 1; rl = row - na;          hr = hb; o = o1; }
  else if (row < na + 2 * nb)      { q = 2; rl = row - na - nb;     hr = hb; o = o2; }
  else if (row < 2 * na + 2 * nb)  { q = 3; rl = row - na - 2 * nb; hr = ha; o = o3; }
  else return;
  hr += (size_t)rl * HID;
  const float* vq = vsh + q * HID * HEADS;
  float s = 0.f;
  for (int k = 0; k < HID; k++) s = fmaf(hr[k], vq[k * HEADS + h], s);
  o[(size_t)rl * HEADS + h] = s;
}

// ================= CSR build (both directions fused) =================
__global__ __launch_bounds__(256) void hist2(
    const int* __restrict__ dst_ab, const int* __restrict__ dst_ba,
    int* __restrict__ cnt_ab, int* __restrict__ cnt_ba, int E)
{
  int gid = blockIdx.x * 256 + threadIdx.x;
  if (gid < E) atomicAdd(&cnt_ab[dst_ab[gid]], 1);
  else if (gid < 2 * E) atomicAdd(&cnt_ba[dst_ba[gid - E]], 1);
}

__global__ __launch_bounds__(1024) void scan2(
    const int* __restrict__ cnt_ab, const int* __restrict__ cnt_ba,
    int* __restrict__ ip_ab, int* __restrict__ ip_ba, int n_ab, int n_ba)
{
  const int* cnt = (blockIdx.x == 0) ? cnt_ab : cnt_ba;
  int* indptr = (blockIdx.x == 0) ? ip_ab : ip_ba;
  int n = (blockIdx.x == 0) ? n_ab : n_ba;
  __shared__ int parts[1024];
  const int tid = threadIdx.x;
  const int base = tid * 10;
  int local[10];
  int s = 0;
#pragma unroll
  for (int j = 0; j < 10; j++) {
    int v = (base + j < n) ? cnt[base + j] : 0;
    local[j] = v; s += v;
  }
  parts[tid] = s;
  __syncthreads();
  for (int off = 1; off < 1024; off <<= 1) {
    int v = (tid >= off) ? parts[tid - off] : 0;
    __syncthreads();
    parts[tid] += v;
    __syncthreads();
  }
  int ex = parts[tid] - s;
#pragma unroll
  for (int j = 0; j < 10; j++) {
    if (base + j < n) indptr[base + j] = ex;
    ex += local[j];
  }
  if (tid == 1023) indptr[n] = parts[1023];
}

__global__ __launch_bounds__(256) void scatter2(
    const int* __restrict__ edge_ab, const int* __restrict__ edge_ba,
    const int* __restrict__ ip_ab, const int* __restrict__ ip_ba,
    int* __restrict__ cur_ab, int* __restrict__ cur_ba,
    int* __restrict__ srcs_ab, int* __restrict__ srcs_ba, int E)
{
  int gid = blockIdx.x * 256 + threadIdx.x;
  if (gid < E) {
    int d = edge_ab[E + gid];
    int pos = ip_ab[d] + atomicAdd(&cur_ab[d], 1);
    srcs_ab[pos] = edge_ab[gid];
  } else if (gid < 2 * E) {
    int g = gid - E;
    int d = edge_ba[E + g];
    int pos = ip_ba[d] + atomicAdd(&cur_ba[d], 1);
    srcs_ba[pos] = edge_ba[g];
  }
}

// ================= wave-per-node segment softmax + aggregation (no barriers/LDS) ===========
struct GDir {
  const int* indptr; const int* srcs;
  const float* als; const float* ald;
  const float* h; float* z;
};

__global__ __launch_bounds__(256) void gat_edge2(GDir d0, GDir d1, int n0, int ntot)
{
  const int w = threadIdx.x >> 6;
  const int lane = threadIdx.x & 63;
  const int g = blockIdx.x * 4 + w;
  if (g >= ntot) return;
  const bool first = (g < n0);
  const int n = first ? g : g - n0;
  const int* indptr = first ? d0.indptr : d1.indptr;
  const int* srcs   = first ? d0.srcs   : d1.srcs;
  const float* als  = first ? d0.als    : d1.als;
  const float* ald  = first ? d0.ald    : d1.ald;
  const float* hsrc = first ? d0.h      : d1.h;
  float* zp = (first ? d0.z : d1.z) + (size_t)n * (HEADS * HID);

  const int base = indptr[n];
  const int deg = indptr[n + 1] - base;
  if (deg == 0) {
#pragma unroll
    for (int hh = 0; hh < HEADS; hh++)
      *(float2*)(zp + hh * HID + 2 * lane) = make_float2(0.f, 0.f);
    return;
  }
  const int eh = lane >> 3, h = lane & 7;  // this lane's (edge-slot, head)
  const float aldn = ald[(size_t)n * HEADS + h];
  const int nch = (deg + 7) >> 3;
  const int ncc = nch < 8 ? nch : 8;       // cached chunks (deg<=64 fully cached)

  // pass 1: gather logits (cached), running max
  float vc[8]; int sc[8];
  float m = -3.4e38f;
#pragma unroll
  for (int c = 0; c < 8; c++) {
    if (c >= ncc) break;
    int e = c * 8 + eh;
    int s = (e < deg) ? srcs[base + e] : -1;
    sc[c] = s;
    float v = -3.4e38f;
    if (s >= 0) {
      v = als[(size_t)s * HEADS + h] + aldn;
      v = v > 0.f ? v : 0.2f * v;
    }
    vc[c] = v;
    m = fmaxf(m, v);
  }
  for (int e0 = 64; e0 < deg; e0 += 8) {   // rare tail (deg>64)
    int e = e0 + eh;
    if (e < deg) {
      int s = srcs[base + e];
      float v = als[(size_t)s * HEADS + h] + aldn;
      v = v > 0.f ? v : 0.2f * v;
      m = fmaxf(m, v);
    }
  }
  m = fmaxf(m, __shfl_xor(m, 8));
  m = fmaxf(m, __shfl_xor(m, 16));
  m = fmaxf(m, __shfl_xor(m, 32));

  // pass 2: exp (cached in place) + denom
  float den = 0.f;
#pragma unroll
  for (int c = 0; c < 8; c++) {
    if (c >= ncc) break;
    float ex = (sc[c] >= 0) ? expf(vc[c] - m) : 0.f;
    vc[c] = ex;
    den += ex;
  }
  for (int e0 = 64; e0 < deg; e0 += 8) {
    int e = e0 + eh;
    if (e < deg) {
      int s = srcs[base + e];
      float v = als[(size_t)s * HEADS + h] + aldn;
      v = v > 0.f ? v : 0.2f * v;
      den += expf(v - m);
    }
  }
  den += __shfl_xor(den, 8);
  den += __shfl_xor(den, 16);
  den += __shfl_xor(den, 32);

  // pass 3: aggregation; lane owns channels (2*lane, 2*lane+1)
  float acc[16];
#pragma unroll
  for (int i = 0; i < 16; i++) acc[i] = 0.f;
#pragma unroll
  for (int c = 0; c < 8; c++) {
    if (c >= ncc) break;
    int elim = deg - c * 8; if (elim > 8) elim = 8;
    for (int e8 = 0; e8 < elim; e8++) {
      int s = __shfl(sc[c], e8 * 8);
      const float2 hv = *(const float2*)(hsrc + (size_t)s * HID + 2 * lane);
#pragma unroll
      for (int hh = 0; hh < 8; hh++) {
        float a = __shfl(vc[c], e8 * 8 + hh);
        acc[2 * hh]     = fmaf(a, hv.x, acc[2 * hh]);
        acc[2 * hh + 1] = fmaf(a, hv.y, acc[2 * hh + 1]);
      }
    }
  }
  for (int e0 = 64; e0 < deg; e0 += 8) {   // rare tail: recompute exps
    int e = e0 + eh;
    int s = (e < deg) ? srcs[base + e] : -1;
    float ex = 0.f;
    if (s >= 0) {
      float v = als[(size_t)s * HEADS + h] + aldn;
      v = v > 0.f ? v : 0.2f * v;
      ex = expf(v - m);
    }
    int elim = deg - e0; if (elim > 8) elim = 8;
    for (int e8 = 0; e8 < elim; e8++) {
      int ss = __shfl(s, e8 * 8);
      const float2 hv = *(const float2*)(hsrc + (size_t)ss * HID + 2 * lane);
#pragma unroll
      for (int hh = 0; hh < 8; hh++) {
        float a = __shfl(ex, e8 * 8 + hh);
        acc[2 * hh]     = fmaf(a, hv.x, acc[2 * hh]);
        acc[2 * hh + 1] = fmaf(a, hv.y, acc[2 * hh + 1]);
      }
    }
  }
  // epilogue: fold 1/(den+eps), write z
#pragma unroll
  for (int hh = 0; hh < 8; hh++) {
    float dh = __shfl(den, hh);   // lane hh holds head hh's denom
    float inv = 1.f / (dh + 1e-16f);
    *(float2*)(zp + hh * HID + 2 * lane) =
        make_float2(acc[2 * hh] * inv, acc[2 * hh + 1] * inv);
  }
}

// ================= pool + FC =================
__global__ __launch_bounds__(256) void pool_dot2(
    const float* __restrict__ ha, const float* __restrict__ hb,
    const int* __restrict__ batch_a, const int* __restrict__ batch_b,
    const float* __restrict__ fc_w, float* __restrict__ gsum, int na, int nb)
{
  const bool isA = blockIdx.x < 160;
  const float* h = isA ? ha : hb;
  const int* batch = isA ? batch_a : batch_b;
  const float* wseg = isA ? fc_w : fc_w + HID;
  float* gs = isA ? gsum : gsum + 8;
  const int n = isA ? na : nb;
  const int b = isA ? blockIdx.x : blockIdx.x - 160;

  __shared__ float sg[8];
  if (threadIdx.x < 8) sg[threadIdx.x] = 0.f;
  __syncthreads();
  const int lane = threadIdx.x & 63;
  const int wv = threadIdx.x >> 6;
  const int gw = b * 4 + wv;
  const int tw = 160 * 4;
  const float2 w2 = *(const float2*)(wseg + lane * 2);
  for (int r = gw; r < n; r += tw) {
    float2 hv = *(const float2*)(h + (size_t)r * HID + lane * 2);
    float s = hv.x * w2.x + hv.y * w2.y;
#pragma unroll
    for (int off = 32; off > 0; off >>= 1) s += __shfl_down(s, off, 64);
    if (lane == 0) atomicAdd(&sg[batch[r]], s);
  }
  __syncthreads();
  if (threadIdx.x < 8) atomicAdd(&gs[threadIdx.x], sg[threadIdx.x]);
}

__global__ __launch_bounds__(64) void finalize_out(
    const float* __restrict__ gsum, const int* __restrict__ batch_a,
    const int* __restrict__ batch_b, const float* __restrict__ fc_b,
    float* __restrict__ out, int na, int nb, int ng)
{
  int g = threadIdx.x;
  if (g >= ng) return;
  int l, r, lo;
  l = 0; r = na; while (l < r) { int m = (l + r) >> 1; if (batch_a[m] < g) l = m + 1; else r = m; } lo = l;
  r = na; while (l < r) { int m = (l + r) >> 1; if (batch_a[m] < g + 1) l = m + 1; else r = m; }
  int ca = l - lo; if (ca < 1) ca = 1;
  l = 0; r = nb; while (l < r) { int m = (l + r) >> 1; if (batch_b[m] < g) l = m + 1; else r = m; } lo = l;
  r = nb; while (l < r) { int m = (l + r) >> 1; if (batch_b[m] < g + 1) l = m + 1; else r = m; }
  int cb = l - lo; if (cb < 1) cb = 1;
  out[g] = gsum[g] / (float)ca + gsum[8 + g] / (float)cb + fc_b[0];
}

extern "C" void kernel_launch(void* const* d_in, const int* in_sizes, int n_in,
                              void* d_out, int out_size, void* d_ws, size_t ws_size,
                              hipStream_t stream)
{
  const float* x_a = (const float*)d_in[0];
  const float* x_b = (const float*)d_in[1];
  const int* edge_ab = (const int*)d_in[2];
  const int* edge_ba = (const int*)d_in[3];
  const int* batch_a = (const int*)d_in[4];
  const int* batch_b = (const int*)d_in[5];
  const float* lin_a_w = (const float*)d_in[6];
  const float* lin_a_b = (const float*)d_in[7];
  const float* lin_b_w = (const float*)d_in[8];
  const float* lin_b_b = (const float*)d_in[9];
  const float* fc_w = (const float*)d_in[10];
  const float* fc_b = (const float*)d_in[11];

  const int NA = in_sizes[4];
  const int NB = in_sizes[5];
  const int E  = in_sizes[2] / 2;
  const int FA = in_sizes[0] / NA;
  const int FB = in_sizes[1] / NB;
  const int NG = out_size;
  const int NMAX = NA > NB ? NA : NB;
  const int NAp = (NA + 127) & ~127, NBp = (NB + 127) & ~127;
  const int yba = NAp / 128, ybb = NBp / 128;
  const int Mtot = NAp + NBp;

  // ---- size model (mirrors carve order) ----
  auto al256 = [](size_t b) { return (b + 255) & ~(size_t)255; };
  size_t fixed = 0;
  fixed += 3 * al256((size_t)NAp * HID * 4) + 3 * al256((size_t)NBp * HID * 4);
  fixed += al256((size_t)NB * HEADS * HID * 4);                                   // z_ab
  fixed += al256((size_t)4 * HEADS * HID * HID * 4);                              // Wp4
  fixed += al256((size_t)8 * HID * HEADS * 4);                                    // vv
  fixed += 2 * al256((size_t)NAp * HEADS * 4) + 2 * al256((size_t)NBp * HEADS * 4);
  fixed += al256(((size_t)4 * NMAX + 16) * 4);
  fixed += al256((size_t)(NB + 1) * 4) + al256((size_t)(NA + 1) * 4);
  fixed += 2 * al256((size_t)E * 4);
  fixed += 8192;
  const size_t zba_sz = al256((size_t)NA * HEADS * HID * 4);
  const size_t pslice = al256((size_t)Mtot * HID * 4);

  int KS = 4; bool dual = true;
  if (fixed + zba_sz + 4 * pslice <= ws_size)      { dual = true;  KS = 4; }
  else if (fixed + zba_sz + 2 * pslice <= ws_size) { dual = true;  KS = 2; }
  else if (fixed + 4 * pslice <= ws_size)          { dual = false; KS = 4; }
  else if (fixed + 2 * pslice <= ws_size)          { dual = false; KS = 2; }
  else if (fixed + 1 * pslice <= ws_size)          { dual = false; KS = 1; }
  else return;  // loud failure (out stays poisoned)

  char* w = (char*)d_ws;
  auto carve = [&](size_t bytes) -> void* {
    void* p = (void*)w;
    w += (bytes + 255) & ~(size_t)255;
    return p;
  };
  float* ha0 = (float*)carve((size_t)NAp * HID * 4);
  float* hb0 = (float*)carve((size_t)NBp * HID * 4);
  float* ha1 = (float*)carve((size_t)NAp * HID * 4);
  float* hb1 = (float*)carve((size_t)NBp * HID * 4);
  float* ha2 = (float*)carve((size_t)NAp * HID * 4);
  float* hb2 = (float*)carve((size_t)NBp * HID * 4);
  float* z_ab = (float*)carve((size_t)NB * HEADS * HID * 4);
  float* z_ba = dual ? (float*)carve((size_t)NA * HEADS * HID * 4) : z_ab;
  float* P    = (float*)carve((size_t)KS * Mtot * HID * 4);
  float* Wp4  = (float*)carve((size_t)4 * HEADS * HID * HID * 4);
  float* vv   = (float*)carve((size_t)8 * HID * HEADS * 4);
  float* als_ab = (float*)carve((size_t)NAp * HEADS * 4);
  float* ald_ab = (float*)carve((size_t)NBp * HEADS * 4);
  float* als_ba = (float*)carve((size_t)NBp * HEADS * 4);
  float* ald_ba = (float*)carve((size_t)NAp * HEADS * 4);
  int* csrblk = (int*)carve(((size_t)4 * NMAX + 16) * 4);
  int* indptr_ab = (int*)carve((size_t)(NB + 1) * 4);
  int* indptr_ba = (int*)carve((size_t)(NA + 1) * 4);
  int* srcs_ab   = (int*)carve((size_t)E * 4);
  int* srcs_ba   = (int*)carve((size_t)E * 4);
  if ((size_t)(w - (char*)d_ws) > ws_size) return;

  int* cnt_ab = csrblk;
  int* cnt_ba = csrblk + NMAX;
  int* cur_ab = csrblk + 2 * NMAX;
  int* cur_ba = csrblk + 3 * NMAX;
  float* gsum = (float*)(csrblk + 4 * NMAX);

  hipMemsetAsync(csrblk, 0, ((size_t)4 * NMAX + 16) * 4, stream);

  // ---- weight prep ----
  PrepArgs pa;
  const int wi_idx[8] = {12, 13, 17, 18, 22, 23, 27, 28};
  const int ai_idx[8] = {14, 15, 19, 20, 24, 25, 29, 30};
  for (int i = 0; i < 8; i++) {
    pa.W[i] = (const float*)d_in[wi_idx[i]];
    pa.a[i] = (const float*)d_in[ai_idx[i]];
    pa.v[i] = vv + (size_t)i * HID * HEADS;
  }
  for (int g = 0; g < 4; g++) pa.Wp[g] = Wp4 + (size_t)g * HEADS * HID * HID;
  prep_weights<<<2048 + 32, 256, 0, stream>>>(pa);

  // ---- CSR both directions ----
  hist2<<<(2 * E + 255) / 256, 256, 0, stream>>>(edge_ab + E, edge_ba + E, cnt_ab, cnt_ba, E);
  scan2<<<2, 1024, 0, stream>>>(cnt_ab, cnt_ba, indptr_ab, indptr_ba, NB, NA);
  scatter2<<<(2 * E + 255) / 256, 256, 0, stream>>>(
      edge_ab, edge_ba, indptr_ab, indptr_ba, cur_ab, cur_ba, srcs_ab, srcs_ba, E);

  const int red_grid = (Mtot * 32 + 255) / 256;
  const GSeg gnone = {nullptr, nullptr, 0, 16, 0};
  const RSeg rnone = {nullptr, nullptr, 0, 0};

  // ---- input linears: one dual-segment split-K launch ----
  {
    GSeg sa = {x_a, lin_a_w, NA, FA, yba};
    GSeg sb = {x_b, lin_b_w, NB, FB, ybb};
    gemm2_splitk<<<dim3(yba + ybb, KS), 256, 0, stream>>>(sa, sb, P, Mtot, KS);
    RSeg ra = {ha0, lin_a_b, NA, 0};
    RSeg rb = {hb0, lin_b_b, NB, yba * 128};
    reduce_epi<<<red_grid, 256, 0, stream>>>(P, Mtot, KS, 1.f, 1, ra, rb);
  }

  // ---- two GAT layers ----
  auto run_layer = [&](int L, const float* haP, const float* hbP,
                       float* haN, float* hbN, const float* b_ab, const float* b_ba,
                       int relu) {
    compute_al4<<<((2 * (NA + NB)) * HEADS + 255) / 256, 256, 0, stream>>>(
        haP, hbP, vv + (size_t)L * 4 * HID * HEADS,
        als_ab, ald_ab, als_ba, ald_ba, NA, NB);
    GDir dab = {indptr_ab, srcs_ab, als_ab, ald_ab, haP, z_ab};
    GDir dba = {indptr_ba, srcs_ba, als_ba, ald_ba, hbP, z_ba};
    const float* Wab = Wp4 + (size_t)(2 * L) * HEADS * HID * HID;
    const float* Wba = Wp4 + (size_t)(2 * L + 1) * HEADS * HID * HID;
    if (dual) {
      gat_edge2<<<(NB + NA + 3) / 4, 256, 0, stream>>>(dab, dba, NB, NB + NA);
      GSeg s0 = {z_ab, Wab, NB, HEADS * HID, ybb};
      GSeg s1 = {z_ba, Wba, NA, HEADS * HID, yba};
      gemm2_splitk<<<dim3(ybb + yba, KS), 256, 0, stream>>>(s0, s1, P, Mtot, KS);
      RSeg r0 = {hbN, b_ab, NB, 0};
      RSeg r1 = {haN, b_ba, NA, ybb * 128};
      reduce_epi<<<red_grid, 256, 0, stream>>>(P, Mtot, KS, 1.f / HEADS, relu, r0, r1);
    } else {
      gat_edge2<<<(NB + 3) / 4, 256, 0, stream>>>(dab, dab, NB, NB);
      GSeg s0 = {z_ab, Wab, NB, HEADS * HID, ybb};
      gemm2_splitk<<<dim3(ybb, KS), 256, 0, stream>>>(s0, gnone, P, NBp, KS);
      RSeg r0 = {hbN, b_ab, NB, 0};
      reduce_epi<<<(NBp * 32 + 255) / 256, 256, 0, stream>>>(P, NBp, KS, 1.f / HEADS, relu, r0, rnone);
      gat_edge2<<<(NA + 3) / 4, 256, 0, stream>>>(dba, dba, NA, NA);
      GSeg s1 = {z_ba, Wba, NA, HEADS * HID, yba};
      gemm2_splitk<<<dim3(yba, KS), 256, 0, stream>>>(s1, gnone, P, NAp, KS);
      RSeg r1 = {haN, b_ba, NA, 0};
      reduce_epi<<<(NAp * 32 + 255) / 256, 256, 0, stream>>>(P, NAp, KS, 1.f / HEADS, relu, r1, rnone);
    }
  };

  run_layer(0, ha0, hb0, ha1, hb1, (const float*)d_in[16], (const float*)d_in[21], 1);
  run_layer(1, ha1, hb1, ha2, hb2, (const float*)d_in[26], (const float*)d_in[31], 0);

  // ---- pooled mean + FC ----
  pool_dot2<<<320, 256, 0, stream>>>(ha2, hb2, batch_a, batch_b, fc_w, gsum, NA, NB);
  finalize_out<<<1, 64, 0, stream>>>(gsum, batch_a, batch_b, fc_b,
                                     (float*)d_out, NA, NB, NG);
}